// Round 6
// baseline (6261.594 us; speedup 1.0000x reference)
//
#include <hip/hip_runtime.h>
#include <math.h>

#define HH 512
#define DD 512
#define BB 64
#define SS 256
#define KK 1024
#define CC 5

typedef __attribute__((ext_vector_type(8))) short short8;
typedef __attribute__((ext_vector_type(4))) float float4v;

// ---- workspace layout (bytes) ----  total 101,188,608 B
#define OFF_XEF     0u               // 256 s x 2 sp x 64 b x 512 k shorts = 33.5 MB
#define OFF_HSPL    33554432u        // [2 sp][2 phase][2 dir][64 b][512 k] shorts
#define OFF_FLG     34078720u        // 256 x 4B flags
#define OFF_HIST    34079744u        // 2 x 256 x 512 x 64 fp32 = 67 MB
#define OFF_POOLED  OFF_HSPL         // pooled overlays hspl (dead after recurrence)
#define HSPL_PLANE  131072           // shorts per split plane

__device__ __forceinline__ unsigned f2bf_bits(float f) {
    unsigned u = __builtin_bit_cast(unsigned, f);
    return (u + 0x7fffu + ((u >> 16) & 1u)) >> 16;   // RNE
}
__device__ __forceinline__ float sigm_(float v) {
    return 1.f / (1.f + expf(-v));
}
__device__ __forceinline__ float tanh_(float v) {
    return tanhf(v);
}

// ---------------------------------------------------------------------------
// Gather embeddings + split hi/lo bf16 into xef[s][sp][b][k].
// ---------------------------------------------------------------------------
__global__ __launch_bounds__(256)
void gather_split_k(const int* __restrict__ x, const float* __restrict__ embed,
                    short* __restrict__ xef)
{
    const int s   = blockIdx.x;
    const int tid = threadIdx.x;
    const int b   = tid & 63;
    const int seg = tid >> 6;            // 4 segs x 128 k
    __shared__ int rows[BB];
    if (tid < BB) rows[tid] = x[tid * SS + s];   // x is [B][S]
    __syncthreads();
    const float* e = embed + (size_t)rows[b] * DD + seg * 128;
    short* oh = xef + ((size_t)(s * 2 + 0) * BB + b) * 512 + seg * 128;
    short* ol = xef + ((size_t)(s * 2 + 1) * BB + b) * 512 + seg * 128;
    for (int k0 = 0; k0 < 128; k0 += 8) {
        const float4 a = *(const float4*)(e + k0);
        const float4 c = *(const float4*)(e + k0 + 4);
        const float ev[8] = {a.x, a.y, a.z, a.w, c.x, c.y, c.z, c.w};
        short8 vh, vl;
        #pragma unroll
        for (int j = 0; j < 8; ++j) {
            const unsigned hib = f2bf_bits(ev[j]);
            const float hif = __builtin_bit_cast(float, hib << 16);
            const unsigned lob = f2bf_bits(ev[j] - hif);
            vh[j] = (short)hib;
            vl[j] = (short)lob;
        }
        *(short8*)(oh + k0) = vh;
        *(short8*)(ol + k0) = vl;
    }
}

// ---------------------------------------------------------------------------
__global__ __launch_bounds__(256)
void zero_k(unsigned* __restrict__ base, int ndw)
{
    int i = blockIdx.x * 256 + threadIdx.x;
    const int stride = gridDim.x * 256;
    for (; i < ndw; i += stride) base[i] = 0u;
}

// ---------------------------------------------------------------------------
// One LSTM step for one direction — EXACT R3-proven body (x-part, spin,
// h-part, exchange, gates, stg, hist, publish, vmcnt, flag), parameterized
// by dir / s / W-half / flag-set. Called twice per iteration (fwd, bwd).
// ---------------------------------------------------------------------------
__device__ __forceinline__ void lstm_phase(
    const short8* wbase, const short* __restrict__ xef,
    short* __restrict__ hspl, float* __restrict__ hist,
    unsigned* myflg, float* exw, unsigned short* stg,
    const float* bias_arr,
    int t, int s, int p, int dir, int wlocal,
    int tid, int lane, int wv, int nn, int quad, int b, int h0)
{
    float4v acc = {0.f, 0.f, 0.f, 0.f};

    // ---------- x-part: contiguous fragment loads from xef ----------
    {
        const short8* xh8 = (const short8*)(xef +
            ((size_t)(s * 2 + 0) * BB + b) * 512 + quad * 8);
        const short8* xl8 = (const short8*)(xef +
            ((size_t)(s * 2 + 1) * BB + b) * 512 + quad * 8);
        #pragma unroll
        for (int kt = 0; kt < 16; ++kt) {
            const short8 xh  = xh8[kt * 4];
            const short8 xl  = xl8[kt * 4];
            const short8 whi = wbase[(0 * 32 + kt) * 64 + lane];
            const short8 wlo = wbase[(1 * 32 + kt) * 64 + lane];
            acc = __builtin_amdgcn_mfma_f32_16x16x32_bf16(whi, xh, acc, 0, 0, 0);
            acc = __builtin_amdgcn_mfma_f32_16x16x32_bf16(whi, xl, acc, 0, 0, 0);
            acc = __builtin_amdgcn_mfma_f32_16x16x32_bf16(wlo, xh, acc, 0, 0, 0);
        }
    }

    // ---------- wait: all 128 WGs finished step t-1 of this dir ----------
    // (observer==loader invariant preserved; light s_sleep backoff)
    if (t > 0) {
        const unsigned tgt = (unsigned)t;
        unsigned va, vb;
        va = __hip_atomic_load(myflg + lane, __ATOMIC_RELAXED,
                               __HIP_MEMORY_SCOPE_AGENT);
        vb = __hip_atomic_load(myflg + 64 + lane, __ATOMIC_RELAXED,
                               __HIP_MEMORY_SCOPE_AGENT);
        while (__any(va < tgt || vb < tgt)) {
            __builtin_amdgcn_s_sleep(4);
            va = __hip_atomic_load(myflg + lane, __ATOMIC_RELAXED,
                                   __HIP_MEMORY_SCOPE_AGENT);
            vb = __hip_atomic_load(myflg + 64 + lane, __ATOMIC_RELAXED,
                                   __HIP_MEMORY_SCOPE_AGENT);
        }
        asm volatile("" ::: "memory");
    }

    // ---------- h-part: agent-scope 8B loads ----------
    {
        const size_t zrow = ((size_t)(p * 2 + dir) * BB + b) * HH + quad * 8;
        const unsigned long long* zhq = (const unsigned long long*)(hspl + zrow);
        const unsigned long long* zlq =
            (const unsigned long long*)(hspl + HSPL_PLANE + zrow);
        #pragma unroll
        for (int kt = 0; kt < 16; ++kt) {
            union { unsigned long long q[2]; short8 v; } uh, ul;
            uh.q[0] = __hip_atomic_load(zhq + kt * 8 + 0, __ATOMIC_RELAXED,
                                        __HIP_MEMORY_SCOPE_AGENT);
            uh.q[1] = __hip_atomic_load(zhq + kt * 8 + 1, __ATOMIC_RELAXED,
                                        __HIP_MEMORY_SCOPE_AGENT);
            ul.q[0] = __hip_atomic_load(zlq + kt * 8 + 0, __ATOMIC_RELAXED,
                                        __HIP_MEMORY_SCOPE_AGENT);
            ul.q[1] = __hip_atomic_load(zlq + kt * 8 + 1, __ATOMIC_RELAXED,
                                        __HIP_MEMORY_SCOPE_AGENT);
            const short8 whi = wbase[(0 * 32 + 16 + kt) * 64 + lane];
            const short8 wlo = wbase[(1 * 32 + 16 + kt) * 64 + lane];
            acc = __builtin_amdgcn_mfma_f32_16x16x32_bf16(whi, uh.v, acc, 0, 0, 0);
            acc = __builtin_amdgcn_mfma_f32_16x16x32_bf16(whi, ul.v, acc, 0, 0, 0);
            acc = __builtin_amdgcn_mfma_f32_16x16x32_bf16(wlo, uh.v, acc, 0, 0, 0);
        }
    }

    // ---------- bias + per-wave exchange ----------
    #pragma unroll
    for (int r2 = 0; r2 < 4; ++r2)
        exw[(quad * 4 + r2) * 16 + nn] = acc[r2] + bias_arr[r2];
    float pg[4];
    #pragma unroll
    for (int g_ = 0; g_ < 4; ++g_)
        pg[g_] = exw[(g_ * 4 + quad) * 16 + nn];

    const float f_  = sigm_(pg[0]);
    const float i_  = sigm_(pg[1]);
    const float ct  = tanh_(pg[2]);
    const float o_  = sigm_(pg[3]);
    const float c_  = (f_ + i_) * ct;      // faithful: prev cell unused
    const float hn  = o_ * tanh_(c_);

    const unsigned hib = f2bf_bits(hn);
    const float hif = __builtin_bit_cast(float, hib << 16);
    const unsigned lob = f2bf_bits(hn - hif);
    stg[(0 * 4 + quad) * 64 + b] = (unsigned short)hib;
    stg[(1 * 4 + quad) * 64 + b] = (unsigned short)lob;
    hist[(((size_t)dir * SS + s) * HH + h0 + quad) * BB + b] = hn;
    __syncthreads();

    // ---------- publish: packed dword write-through stores ----------
    {
        const int plane = tid >> 7;          // 0 hi, 1 lo
        const int d     = tid & 127;
        const int pb    = d >> 1;
        const int pair  = d & 1;
        const unsigned v0 = stg[(plane * 4 + pair * 2 + 0) * 64 + pb];
        const unsigned v1 = stg[(plane * 4 + pair * 2 + 1) * 64 + pb];
        const unsigned val = v0 | (v1 << 16);
        const size_t soff = ((size_t)((p ^ 1) * 2 + dir) * BB + pb) * HH
                            + h0 + pair * 2;
        unsigned* dst = (unsigned*)(hspl + (size_t)plane * HSPL_PLANE + soff);
        __hip_atomic_store(dst, val, __ATOMIC_RELAXED,
                           __HIP_MEMORY_SCOPE_AGENT);
    }
    asm volatile("s_waitcnt vmcnt(0)" ::: "memory");
    __syncthreads();
    if (tid == 0)
        __hip_atomic_store(myflg + wlocal, (unsigned)(t + 1),
                           __ATOMIC_RELAXED, __HIP_MEMORY_SCOPE_AGENT);
}

// ---------------------------------------------------------------------------
// Cooperative recurrence: R13 dual-chain interleave. 128 WGs x 256 thr; each
// WG owns 4 h of fwd AND 4 h of bwd (W-LDS 64+64 = 128 KB). Per iteration:
// phase F (fwd step t) then phase B (bwd step t). Each chain's flag
// propagation (P) is hidden behind the OTHER chain's entire phase, so the
// per-step wait collapses; per-iteration cost ~= 2*(compute + publish-ack).
// Each phase body is the proven R3 text verbatim (lstm_phase above).
// ---------------------------------------------------------------------------
__global__ void __launch_bounds__(256, 1)
bilstm_recur_k(const short* __restrict__ xef,
               const float* __restrict__ fwd_W, const float* __restrict__ bwd_W,
               const float* __restrict__ fwd_b, const float* __restrict__ bwd_b,
               short* __restrict__ hspl, float* __restrict__ hist,
               unsigned* __restrict__ flg)
{
    extern __shared__ char smem[];
    short8* wlds = (short8*)smem;                            // 128 KB (2 dirs)
    float*  ex   = (float*)(smem + 131072);                  // 4 KB exchange
    unsigned short* stg = (unsigned short*)(smem + 135168);  // 1 KB stage

    const int wlocal = blockIdx.x;       // 0..127
    const int h0     = wlocal << 2;
    const int tid    = threadIdx.x;
    const int lane   = tid & 63;
    const int wv     = __builtin_amdgcn_readfirstlane(tid >> 6);
    const int nn     = lane & 15;
    const int quad   = lane >> 4;
    const int b      = (wv << 4) + nn;

    // ---- pack this WG's W fragments for BOTH dirs into LDS (bit-identical
    //      per-dir to the R3 pack) ----
    for (int d = 0; d < 2; ++d) {
        const float* W = d ? bwd_W : fwd_W;
        short8* wdst = wlds + (size_t)d * 4096;   // 2 planes x 32 kt x 64 lanes
        const int m  = lane & 15;
        const int g  = m >> 2;
        const int hh = m & 3;
        const float* wrow = W + ((size_t)g * HH + h0 + hh) * KK + quad * 8;
        for (int kk = 0; kk < 8; ++kk) {
            const int kt = wv * 8 + kk;          // 4 waves x 8 = 32 kt
            const float4 a  = *(const float4*)(wrow + kt * 32);
            const float4 c4 = *(const float4*)(wrow + kt * 32 + 4);
            const float ev[8] = {a.x, a.y, a.z, a.w, c4.x, c4.y, c4.z, c4.w};
            short8 vh, vl;
            #pragma unroll
            for (int j = 0; j < 8; ++j) {
                const unsigned hib = f2bf_bits(ev[j]);
                const float hif = __builtin_bit_cast(float, hib << 16);
                const unsigned lob = f2bf_bits(ev[j] - hif);
                vh[j] = (short)hib;
                vl[j] = (short)lob;
            }
            wdst[(0 * 32 + kt) * 64 + lane] = vh;
            wdst[(1 * 32 + kt) * 64 + lane] = vl;
        }
    }
    __syncthreads();

    const float4 bvf = *(const float4*)(fwd_b + quad * HH + h0);
    const float4 bvb = *(const float4*)(bwd_b + quad * HH + h0);
    const float biasf[4] = {bvf.x, bvf.y, bvf.z, bvf.w};
    const float biasb[4] = {bvb.x, bvb.y, bvb.z, bvb.w};

    float* exw = ex + wv * 256;

    for (int t = 0; t < SS; ++t) {
        const int sf = t;
        const int sb = SS - 1 - t;
        const int p  = t & 1;
        // phase F: fwd step t
        lstm_phase(wlds, xef, hspl, hist, flg, exw, stg, biasf,
                   t, sf, p, 0, wlocal, tid, lane, wv, nn, quad, b, h0);
        // phase B: bwd step t (independent chain — hides F's propagation)
        lstm_phase(wlds + 4096, xef, hspl, hist, flg + 128, exw, stg, biasb,
                   t, sb, p, 1, wlocal, tid, lane, wv, nn, quad, b, h0);
    }
}

// ---------------------------------------------------------------------------
__global__ __launch_bounds__(256)
void pool_k(const float* __restrict__ hist, float* __restrict__ pooled)
{
    const int i = blockIdx.x * 256 + threadIdx.x;   // i = h*64 + b
    float m = -2.0f;
    for (int s = 0; s < SS; ++s) {
        const float a = hist[(size_t)s * (HH * BB) + i];
        const float c = hist[(size_t)(SS + s) * (HH * BB) + i];
        m = fmaxf(m, tanhf(a * c));
    }
    pooled[i] = m;
}

__global__ __launch_bounds__(256)
void outgemm_k(const float* __restrict__ pooled, const float* __restrict__ Wout,
               const float* __restrict__ bout, float* __restrict__ out)
{
    const int c   = blockIdx.x;
    const int tid = threadIdx.x;
    const int b   = tid & 63;
    const int q   = __builtin_amdgcn_readfirstlane(tid >> 6);
    float p = 0.0f;
    for (int j = 0; j < 128; ++j) {
        const int h = q * 128 + j;
        p = fmaf(pooled[(size_t)h * BB + b], Wout[c * HH + h], p);
    }
    __shared__ float red[4][BB];
    red[q][b] = p;
    __syncthreads();
    if (tid < BB)
        out[tid * CC + c] = red[0][tid] + red[1][tid] + red[2][tid] + red[3][tid] + bout[c];
}

// ---------------------------------------------------------------------------
extern "C" void kernel_launch(void* const* d_in, const int* in_sizes, int n_in,
                              void* d_out, int out_size, void* d_ws, size_t ws_size,
                              hipStream_t stream)
{
    const int*   x     = (const int*)d_in[0];
    const float* embed = (const float*)d_in[1];
    const float* fwd_W = (const float*)d_in[2];
    const float* fwd_b = (const float*)d_in[3];
    const float* bwd_W = (const float*)d_in[4];
    const float* bwd_b = (const float*)d_in[5];
    const float* Wout  = (const float*)d_in[6];
    const float* bout  = (const float*)d_in[7];
    float* out = (float*)d_out;

    char* wsb = (char*)d_ws;
    short*    xef    = (short*)(wsb + OFF_XEF);
    short*    hspl   = (short*)(wsb + OFF_HSPL);
    unsigned* flg    = (unsigned*)(wsb + OFF_FLG);
    float*    hist   = (float*)(wsb + OFF_HIST);
    float*    pooled = (float*)(wsb + OFF_POOLED);   // overlays hspl (dead)

    gather_split_k<<<SS, 256, 0, stream>>>(x, embed, xef);
    zero_k<<<512, 256, 0, stream>>>((unsigned*)(wsb + OFF_HSPL),
                                    (int)((524288 + 1024) / 4));

    hipFuncSetAttribute((const void*)bilstm_recur_k,
                        hipFuncAttributeMaxDynamicSharedMemorySize, 136192);
    void* args[] = {(void*)&xef, (void*)&fwd_W, (void*)&bwd_W,
                    (void*)&fwd_b, (void*)&bwd_b,
                    (void*)&hspl, (void*)&hist, (void*)&flg};
    hipLaunchCooperativeKernel((void*)bilstm_recur_k, dim3(128), dim3(256),
                               args, 136192, stream);

    pool_k<<<128, 256, 0, stream>>>(hist, pooled);
    outgemm_k<<<CC, 256, 0, stream>>>(pooled, Wout, bout, out);
}

// Round 7
// 4110.559 us; speedup vs baseline: 1.5233x; 1.5233x over previous
//
#include <hip/hip_runtime.h>
#include <math.h>

#define HH 512
#define DD 512
#define BB 64
#define SS 256
#define KK 1024
#define CC 5

typedef __attribute__((ext_vector_type(8))) short short8;
typedef __attribute__((ext_vector_type(4))) float float4v;

// ---- workspace layout (bytes) ----  total 101,188,608 B
#define OFF_XEF     0u               // 256 s x 2 sp x 64 b x 512 k shorts = 33.5 MB
#define OFF_HSPL    33554432u        // [2 sp][2 phase][2 dir][64 b][512 k] shorts
#define OFF_FLG     34078720u        // 256 x 4B flags
#define OFF_HIST    34079744u        // 2 x 256 x 512 x 64 fp32 = 67 MB
#define OFF_POOLED  OFF_HSPL         // pooled overlays hspl (dead after recurrence)
#define HSPL_PLANE  131072           // shorts per split plane

__device__ __forceinline__ unsigned f2bf_bits(float f) {
    unsigned u = __builtin_bit_cast(unsigned, f);
    return (u + 0x7fffu + ((u >> 16) & 1u)) >> 16;   // RNE
}
__device__ __forceinline__ float sigm_(float v) {
    return 1.f / (1.f + expf(-v));
}
__device__ __forceinline__ float tanh_(float v) {
    return tanhf(v);
}

// ---------------------------------------------------------------------------
// Gather embeddings + split hi/lo bf16 into xef[s][sp][b][k].
// ---------------------------------------------------------------------------
__global__ __launch_bounds__(256)
void gather_split_k(const int* __restrict__ x, const float* __restrict__ embed,
                    short* __restrict__ xef)
{
    const int s   = blockIdx.x;
    const int tid = threadIdx.x;
    const int b   = tid & 63;
    const int seg = tid >> 6;            // 4 segs x 128 k
    __shared__ int rows[BB];
    if (tid < BB) rows[tid] = x[tid * SS + s];   // x is [B][S]
    __syncthreads();
    const float* e = embed + (size_t)rows[b] * DD + seg * 128;
    short* oh = xef + ((size_t)(s * 2 + 0) * BB + b) * 512 + seg * 128;
    short* ol = xef + ((size_t)(s * 2 + 1) * BB + b) * 512 + seg * 128;
    for (int k0 = 0; k0 < 128; k0 += 8) {
        const float4 a = *(const float4*)(e + k0);
        const float4 c = *(const float4*)(e + k0 + 4);
        const float ev[8] = {a.x, a.y, a.z, a.w, c.x, c.y, c.z, c.w};
        short8 vh, vl;
        #pragma unroll
        for (int j = 0; j < 8; ++j) {
            const unsigned hib = f2bf_bits(ev[j]);
            const float hif = __builtin_bit_cast(float, hib << 16);
            const unsigned lob = f2bf_bits(ev[j] - hif);
            vh[j] = (short)hib;
            vl[j] = (short)lob;
        }
        *(short8*)(oh + k0) = vh;
        *(short8*)(ol + k0) = vl;
    }
}

// ---------------------------------------------------------------------------
__global__ __launch_bounds__(256)
void zero_k(unsigned* __restrict__ base, int ndw)
{
    int i = blockIdx.x * 256 + threadIdx.x;
    const int stride = gridDim.x * 256;
    for (; i < ndw; i += stride) base[i] = 0u;
}

// ---------------------------------------------------------------------------
// Cooperative recurrence: R14 x/h wave split. 256 WGs x 512 thr (8 waves =
// 2 waves/SIMD). Waves 0-3 ("x-role") run the x-part chain; waves 4-7
// ("h-role", same b-blocks) run spin + h-part chain CONCURRENTLY on the same
// SIMDs — hardware TLP overlaps the two serial memory chains that R6 proved
// are the whole cost (wait==0, body==12us serial at 1 wave/SIMD). All load
// patterns, spin (observer==loader), publish->vmcnt->barrier->flag protocol
// are the R3-proven text. New: cross-wave acc exchange via LDS + 1 barrier.
// ---------------------------------------------------------------------------
__global__ void __launch_bounds__(512, 1)
bilstm_recur_k(const short* __restrict__ xef,
               const float* __restrict__ fwd_W, const float* __restrict__ bwd_W,
               const float* __restrict__ fwd_b, const float* __restrict__ bwd_b,
               short* __restrict__ hspl, float* __restrict__ hist,
               unsigned* __restrict__ flg)
{
    extern __shared__ char smem[];
    short8* wlds = (short8*)smem;                          // 64 KB W fragments
    float*  ex   = (float*)(smem + 65536);                 // 8 KB: [role][wb][256]
    unsigned short* stg = (unsigned short*)(smem + 73728); // 1 KB publish stage

    const int w      = blockIdx.x;
    const int dir    = w >> 7;
    const int wlocal = w & 127;
    const int h0     = wlocal << 2;
    const int tid    = threadIdx.x;
    const int lane   = tid & 63;
    const int wv     = __builtin_amdgcn_readfirstlane(tid >> 6);  // 0..7
    const int role   = wv >> 2;          // 0 = x-chain, 1 = h-chain
    const int wb     = wv & 3;           // b-block
    const int nn     = lane & 15;
    const int quad   = lane >> 4;
    const int b      = (wb << 4) + nn;

    // ---- pack this WG's W fragments straight into LDS (bit-identical to
    //      R3's pack; 8 waves x 4 kt instead of 4 waves x 8 kt) ----
    {
        const float* W = dir ? bwd_W : fwd_W;
        const int m  = lane & 15;
        const int g  = m >> 2;
        const int hh = m & 3;
        const float* wrow = W + ((size_t)g * HH + h0 + hh) * KK + quad * 8;
        for (int kk = 0; kk < 4; ++kk) {
            const int kt = wv * 4 + kk;          // 8 waves x 4 = 32 kt
            const float4 a  = *(const float4*)(wrow + kt * 32);
            const float4 c4 = *(const float4*)(wrow + kt * 32 + 4);
            const float ev[8] = {a.x, a.y, a.z, a.w, c4.x, c4.y, c4.z, c4.w};
            short8 vh, vl;
            #pragma unroll
            for (int j = 0; j < 8; ++j) {
                const unsigned hib = f2bf_bits(ev[j]);
                const float hif = __builtin_bit_cast(float, hib << 16);
                const unsigned lob = f2bf_bits(ev[j] - hif);
                vh[j] = (short)hib;
                vl[j] = (short)lob;
            }
            wlds[(0 * 32 + kt) * 64 + lane] = vh;
            wlds[(1 * 32 + kt) * 64 + lane] = vl;
        }
    }
    __syncthreads();

    const float* bi = dir ? bwd_b : fwd_b;
    const float4 biasv = *(const float4*)(bi + quad * HH + h0);
    const float bias_arr[4] = {biasv.x, biasv.y, biasv.z, biasv.w};

    unsigned* myflg = flg + dir * 128;
    float* exX = ex + wb * 256;          // x-role partials (bias included)
    float* exH = ex + 1024 + wb * 256;   // h-role partials

    for (int t = 0; t < SS; ++t) {
        const int s = dir ? (SS - 1 - t) : t;
        const int p = t & 1;

        float4v acc = {0.f, 0.f, 0.f, 0.f};

        if (role == 0) {
            // ---------- x-part: contiguous fragment loads from xef ----------
            const short8* xh8 = (const short8*)(xef +
                ((size_t)(s * 2 + 0) * BB + b) * 512 + quad * 8);
            const short8* xl8 = (const short8*)(xef +
                ((size_t)(s * 2 + 1) * BB + b) * 512 + quad * 8);
            #pragma unroll
            for (int kt = 0; kt < 16; ++kt) {
                const short8 xh  = xh8[kt * 4];
                const short8 xl  = xl8[kt * 4];
                const short8 whi = wlds[(0 * 32 + kt) * 64 + lane];
                const short8 wlo = wlds[(1 * 32 + kt) * 64 + lane];
                acc = __builtin_amdgcn_mfma_f32_16x16x32_bf16(whi, xh, acc, 0, 0, 0);
                acc = __builtin_amdgcn_mfma_f32_16x16x32_bf16(whi, xl, acc, 0, 0, 0);
                acc = __builtin_amdgcn_mfma_f32_16x16x32_bf16(wlo, xh, acc, 0, 0, 0);
            }
            #pragma unroll
            for (int r2 = 0; r2 < 4; ++r2)
                exX[(quad * 4 + r2) * 16 + nn] = acc[r2] + bias_arr[r2];
        } else {
            // ---------- wait: observer==loader (R3-proven spin) ----------
            if (t > 0) {
                const unsigned tgt = (unsigned)t;
                unsigned va, vb;
                va = __hip_atomic_load(myflg + lane, __ATOMIC_RELAXED,
                                       __HIP_MEMORY_SCOPE_AGENT);
                vb = __hip_atomic_load(myflg + 64 + lane, __ATOMIC_RELAXED,
                                       __HIP_MEMORY_SCOPE_AGENT);
                while (__any(va < tgt || vb < tgt)) {
                    __builtin_amdgcn_s_sleep(8);
                    va = __hip_atomic_load(myflg + lane, __ATOMIC_RELAXED,
                                           __HIP_MEMORY_SCOPE_AGENT);
                    vb = __hip_atomic_load(myflg + 64 + lane, __ATOMIC_RELAXED,
                                           __HIP_MEMORY_SCOPE_AGENT);
                }
                asm volatile("" ::: "memory");
            }

            // ---------- h-part: agent-scope 8B loads (R3-proven text) ------
            const size_t zrow = ((size_t)(p * 2 + dir) * BB + b) * HH + quad * 8;
            const unsigned long long* zhq = (const unsigned long long*)(hspl + zrow);
            const unsigned long long* zlq =
                (const unsigned long long*)(hspl + HSPL_PLANE + zrow);
            #pragma unroll
            for (int kt = 0; kt < 16; ++kt) {
                union { unsigned long long q[2]; short8 v; } uh, ul;
                uh.q[0] = __hip_atomic_load(zhq + kt * 8 + 0, __ATOMIC_RELAXED,
                                            __HIP_MEMORY_SCOPE_AGENT);
                uh.q[1] = __hip_atomic_load(zhq + kt * 8 + 1, __ATOMIC_RELAXED,
                                            __HIP_MEMORY_SCOPE_AGENT);
                ul.q[0] = __hip_atomic_load(zlq + kt * 8 + 0, __ATOMIC_RELAXED,
                                            __HIP_MEMORY_SCOPE_AGENT);
                ul.q[1] = __hip_atomic_load(zlq + kt * 8 + 1, __ATOMIC_RELAXED,
                                            __HIP_MEMORY_SCOPE_AGENT);
                const short8 whi = wlds[(0 * 32 + 16 + kt) * 64 + lane];
                const short8 wlo = wlds[(1 * 32 + 16 + kt) * 64 + lane];
                acc = __builtin_amdgcn_mfma_f32_16x16x32_bf16(whi, uh.v, acc, 0, 0, 0);
                acc = __builtin_amdgcn_mfma_f32_16x16x32_bf16(whi, ul.v, acc, 0, 0, 0);
                acc = __builtin_amdgcn_mfma_f32_16x16x32_bf16(wlo, uh.v, acc, 0, 0, 0);
            }
            #pragma unroll
            for (int r2 = 0; r2 < 4; ++r2)
                exH[(quad * 4 + r2) * 16 + nn] = acc[r2];
        }
        __syncthreads();

        // ---------- gates + stage + hist: waves 0-3 (same thread->(h,b)
        //            mapping as R3) ----------
        if (tid < 256) {
            float pg[4];
            #pragma unroll
            for (int g_ = 0; g_ < 4; ++g_)
                pg[g_] = exX[(g_ * 4 + quad) * 16 + nn]
                       + exH[(g_ * 4 + quad) * 16 + nn];

            const float f_  = sigm_(pg[0]);
            const float i_  = sigm_(pg[1]);
            const float ct  = tanh_(pg[2]);
            const float o_  = sigm_(pg[3]);
            const float c_  = (f_ + i_) * ct;      // faithful: prev cell unused
            const float hn  = o_ * tanh_(c_);

            const unsigned hib = f2bf_bits(hn);
            const float hif = __builtin_bit_cast(float, hib << 16);
            const unsigned lob = f2bf_bits(hn - hif);
            stg[(0 * 4 + quad) * 64 + b] = (unsigned short)hib;
            stg[(1 * 4 + quad) * 64 + b] = (unsigned short)lob;
            hist[(((size_t)dir * SS + s) * HH + h0 + quad) * BB + b] = hn;
        }
        __syncthreads();

        // ---------- publish: packed dword write-through stores (R3 text) ----
        if (tid < 256) {
            const int plane = tid >> 7;          // 0 hi, 1 lo
            const int d     = tid & 127;
            const int pb    = d >> 1;
            const int pair  = d & 1;
            const unsigned v0 = stg[(plane * 4 + pair * 2 + 0) * 64 + pb];
            const unsigned v1 = stg[(plane * 4 + pair * 2 + 1) * 64 + pb];
            const unsigned val = v0 | (v1 << 16);
            const size_t soff = ((size_t)((p ^ 1) * 2 + dir) * BB + pb) * HH
                                + h0 + pair * 2;
            unsigned* dst = (unsigned*)(hspl + (size_t)plane * HSPL_PLANE + soff);
            __hip_atomic_store(dst, val, __ATOMIC_RELAXED,
                               __HIP_MEMORY_SCOPE_AGENT);
        }
        asm volatile("s_waitcnt vmcnt(0)" ::: "memory");
        __syncthreads();
        if (tid == 0)
            __hip_atomic_store(myflg + wlocal, (unsigned)(t + 1),
                               __ATOMIC_RELAXED, __HIP_MEMORY_SCOPE_AGENT);
    }
}

// ---------------------------------------------------------------------------
__global__ __launch_bounds__(256)
void pool_k(const float* __restrict__ hist, float* __restrict__ pooled)
{
    const int i = blockIdx.x * 256 + threadIdx.x;   // i = h*64 + b
    float m = -2.0f;
    for (int s = 0; s < SS; ++s) {
        const float a = hist[(size_t)s * (HH * BB) + i];
        const float c = hist[(size_t)(SS + s) * (HH * BB) + i];
        m = fmaxf(m, tanhf(a * c));
    }
    pooled[i] = m;
}

__global__ __launch_bounds__(256)
void outgemm_k(const float* __restrict__ pooled, const float* __restrict__ Wout,
               const float* __restrict__ bout, float* __restrict__ out)
{
    const int c   = blockIdx.x;
    const int tid = threadIdx.x;
    const int b   = tid & 63;
    const int q   = __builtin_amdgcn_readfirstlane(tid >> 6);
    float p = 0.0f;
    for (int j = 0; j < 128; ++j) {
        const int h = q * 128 + j;
        p = fmaf(pooled[(size_t)h * BB + b], Wout[c * HH + h], p);
    }
    __shared__ float red[4][BB];
    red[q][b] = p;
    __syncthreads();
    if (tid < BB)
        out[tid * CC + c] = red[0][tid] + red[1][tid] + red[2][tid] + red[3][tid] + bout[c];
}

// ---------------------------------------------------------------------------
extern "C" void kernel_launch(void* const* d_in, const int* in_sizes, int n_in,
                              void* d_out, int out_size, void* d_ws, size_t ws_size,
                              hipStream_t stream)
{
    const int*   x     = (const int*)d_in[0];
    const float* embed = (const float*)d_in[1];
    const float* fwd_W = (const float*)d_in[2];
    const float* fwd_b = (const float*)d_in[3];
    const float* bwd_W = (const float*)d_in[4];
    const float* bwd_b = (const float*)d_in[5];
    const float* Wout  = (const float*)d_in[6];
    const float* bout  = (const float*)d_in[7];
    float* out = (float*)d_out;

    char* wsb = (char*)d_ws;
    short*    xef    = (short*)(wsb + OFF_XEF);
    short*    hspl   = (short*)(wsb + OFF_HSPL);
    unsigned* flg    = (unsigned*)(wsb + OFF_FLG);
    float*    hist   = (float*)(wsb + OFF_HIST);
    float*    pooled = (float*)(wsb + OFF_POOLED);   // overlays hspl (dead)

    gather_split_k<<<SS, 256, 0, stream>>>(x, embed, xef);
    zero_k<<<512, 256, 0, stream>>>((unsigned*)(wsb + OFF_HSPL),
                                    (int)((524288 + 1024) / 4));

    hipFuncSetAttribute((const void*)bilstm_recur_k,
                        hipFuncAttributeMaxDynamicSharedMemorySize, 74752);
    void* args[] = {(void*)&xef, (void*)&fwd_W, (void*)&bwd_W,
                    (void*)&fwd_b, (void*)&bwd_b,
                    (void*)&hspl, (void*)&hist, (void*)&flg};
    hipLaunchCooperativeKernel((void*)bilstm_recur_k, dim3(256), dim3(512),
                               args, 74752, stream);

    pool_k<<<128, 256, 0, stream>>>(hist, pooled);
    outgemm_k<<<CC, 256, 0, stream>>>(pooled, Wout, bout, out);
}

// Round 8
// 3198.768 us; speedup vs baseline: 1.9575x; 1.2850x over previous
//
#include <hip/hip_runtime.h>
#include <math.h>

#define HH 512
#define DD 512
#define BB 64
#define SS 256
#define KK 1024
#define CC 5

typedef __attribute__((ext_vector_type(8))) short short8;
typedef __attribute__((ext_vector_type(4))) float float4v;

// ---- workspace layout (bytes) ----  total 101,188,608 B
#define OFF_XEF     0u               // 256 s x 2 sp x 64 b x 512 k shorts = 33.5 MB
#define OFF_HSPL    33554432u        // [2 sp][2 phase][2 dir][64 b][512 k] shorts
#define OFF_FLG     34078720u        // 256 x 4B flags
#define OFF_HIST    34079744u        // 2 x 256 x 512 x 64 fp32 = 67 MB
#define OFF_POOLED  OFF_HSPL         // pooled overlays hspl (dead after recurrence)
#define HSPL_PLANE  131072           // shorts per split plane

__device__ __forceinline__ unsigned f2bf_bits(float f) {
    unsigned u = __builtin_bit_cast(unsigned, f);
    return (u + 0x7fffu + ((u >> 16) & 1u)) >> 16;   // RNE
}
__device__ __forceinline__ float sigm_(float v) {
    return 1.f / (1.f + expf(-v));
}
__device__ __forceinline__ float tanh_(float v) {
    return tanhf(v);
}

// ---------------------------------------------------------------------------
// Gather embeddings + split hi/lo bf16 into xef[s][sp][b][k].
// ---------------------------------------------------------------------------
__global__ __launch_bounds__(256)
void gather_split_k(const int* __restrict__ x, const float* __restrict__ embed,
                    short* __restrict__ xef)
{
    const int s   = blockIdx.x;
    const int tid = threadIdx.x;
    const int b   = tid & 63;
    const int seg = tid >> 6;            // 4 segs x 128 k
    __shared__ int rows[BB];
    if (tid < BB) rows[tid] = x[tid * SS + s];   // x is [B][S]
    __syncthreads();
    const float* e = embed + (size_t)rows[b] * DD + seg * 128;
    short* oh = xef + ((size_t)(s * 2 + 0) * BB + b) * 512 + seg * 128;
    short* ol = xef + ((size_t)(s * 2 + 1) * BB + b) * 512 + seg * 128;
    for (int k0 = 0; k0 < 128; k0 += 8) {
        const float4 a = *(const float4*)(e + k0);
        const float4 c = *(const float4*)(e + k0 + 4);
        const float ev[8] = {a.x, a.y, a.z, a.w, c.x, c.y, c.z, c.w};
        short8 vh, vl;
        #pragma unroll
        for (int j = 0; j < 8; ++j) {
            const unsigned hib = f2bf_bits(ev[j]);
            const float hif = __builtin_bit_cast(float, hib << 16);
            const unsigned lob = f2bf_bits(ev[j] - hif);
            vh[j] = (short)hib;
            vl[j] = (short)lob;
        }
        *(short8*)(oh + k0) = vh;
        *(short8*)(ol + k0) = vl;
    }
}

// ---------------------------------------------------------------------------
__global__ __launch_bounds__(256)
void zero_k(unsigned* __restrict__ base, int ndw)
{
    int i = blockIdx.x * 256 + threadIdx.x;
    const int stride = gridDim.x * 256;
    for (; i < ndw; i += stride) base[i] = 0u;
}

// ---------------------------------------------------------------------------
// Cooperative recurrence: 256 WGs x 256 thr (1 WG/CU). R15 = R3-proven body
// with ONE change: the h-part's 64 agent-scope loads are issued as ONE batch
// into 64 individually NAMED u64 registers (no arrays) before any h-MFMA.
// Cycle accounting across R3-R7 shows the body is ~32 exposed ~650cy load
// round-trips (VGPR=36 caps pipeline depth at ~2); this raises h-chain depth
// to 16. Accumulation order is bit-identical to R3 (kt ascending,
// whi*uh / whi*ul / wlo*uh). x-part, spin, hist position, publish, flag:
// byte-identical to R3. This also bisects R1's failing bundle (h-staging
// alone): a 1.0376e-03 failure here would identify h-staging as the breaker.
// ---------------------------------------------------------------------------
__global__ void __launch_bounds__(256, 1)
bilstm_recur_k(const short* __restrict__ xef,
               const float* __restrict__ fwd_W, const float* __restrict__ bwd_W,
               const float* __restrict__ fwd_b, const float* __restrict__ bwd_b,
               short* __restrict__ hspl, float* __restrict__ hist,
               unsigned* __restrict__ flg)
{
    extern __shared__ char smem[];
    short8* wlds = (short8*)smem;                          // 64 KB W fragments
    float*  ex   = (float*)(smem + 65536);                 // 4 KB exchange
    unsigned short* stg = (unsigned short*)(smem + 69632); // 1 KB publish stage

    const int w      = blockIdx.x;
    const int dir    = w >> 7;
    const int wlocal = w & 127;
    const int h0     = wlocal << 2;
    const int tid    = threadIdx.x;
    const int lane   = tid & 63;
    const int wv     = __builtin_amdgcn_readfirstlane(tid >> 6);
    const int n0     = wv << 4;
    const int nn     = lane & 15;
    const int quad   = lane >> 4;

    // ---- pack this WG's W fragments straight into LDS (bit-identical to
    //      wpack_k: f2bf_bits split of W[(g*H+h0+hh)][kt*32+quad*8+j]) ----
    {
        const float* W = dir ? bwd_W : fwd_W;
        const int m  = lane & 15;
        const int g  = m >> 2;
        const int hh = m & 3;
        const float* wrow = W + ((size_t)g * HH + h0 + hh) * KK + quad * 8;
        for (int kk = 0; kk < 8; ++kk) {
            const int kt = wv * 8 + kk;          // 4 waves x 8 = 32 kt
            const float4 a  = *(const float4*)(wrow + kt * 32);
            const float4 c4 = *(const float4*)(wrow + kt * 32 + 4);
            const float ev[8] = {a.x, a.y, a.z, a.w, c4.x, c4.y, c4.z, c4.w};
            short8 vh, vl;
            #pragma unroll
            for (int j = 0; j < 8; ++j) {
                const unsigned hib = f2bf_bits(ev[j]);
                const float hif = __builtin_bit_cast(float, hib << 16);
                const unsigned lob = f2bf_bits(ev[j] - hif);
                vh[j] = (short)hib;
                vl[j] = (short)lob;
            }
            wlds[(0 * 32 + kt) * 64 + lane] = vh;
            wlds[(1 * 32 + kt) * 64 + lane] = vl;
        }
    }
    __syncthreads();

    const float* bi = dir ? bwd_b : fwd_b;
    const float4 biasv = *(const float4*)(bi + quad * HH + h0);
    const float bias_arr[4] = {biasv.x, biasv.y, biasv.z, biasv.w};

    unsigned* myflg = flg + dir * 128;
    float* exw = ex + wv * 256;
    const int b = n0 + nn;
    const int h = h0 + quad;

    for (int t = 0; t < SS; ++t) {
        const int s = dir ? (SS - 1 - t) : t;
        const int p = t & 1;

        float4v acc = {0.f, 0.f, 0.f, 0.f};

        // ---------- x-part: contiguous fragment loads from xef ----------
        {
            const short8* xh8 = (const short8*)(xef +
                ((size_t)(s * 2 + 0) * BB + b) * 512 + quad * 8);
            const short8* xl8 = (const short8*)(xef +
                ((size_t)(s * 2 + 1) * BB + b) * 512 + quad * 8);
            #pragma unroll
            for (int kt = 0; kt < 16; ++kt) {
                const short8 xh  = xh8[kt * 4];
                const short8 xl  = xl8[kt * 4];
                const short8 whi = wlds[(0 * 32 + kt) * 64 + lane];
                const short8 wlo = wlds[(1 * 32 + kt) * 64 + lane];
                acc = __builtin_amdgcn_mfma_f32_16x16x32_bf16(whi, xh, acc, 0, 0, 0);
                acc = __builtin_amdgcn_mfma_f32_16x16x32_bf16(whi, xl, acc, 0, 0, 0);
                acc = __builtin_amdgcn_mfma_f32_16x16x32_bf16(wlo, xh, acc, 0, 0, 0);
            }
        }

        // ---------- wait: all WGs of this dir finished step t-1 ----------
        if (t > 0) {
            const unsigned tgt = (unsigned)t;
            unsigned va, vb;
            va = __hip_atomic_load(myflg + lane, __ATOMIC_RELAXED,
                                   __HIP_MEMORY_SCOPE_AGENT);
            vb = __hip_atomic_load(myflg + 64 + lane, __ATOMIC_RELAXED,
                                   __HIP_MEMORY_SCOPE_AGENT);
            while (__any(va < tgt || vb < tgt)) {
                __builtin_amdgcn_s_sleep(32);
                va = __hip_atomic_load(myflg + lane, __ATOMIC_RELAXED,
                                       __HIP_MEMORY_SCOPE_AGENT);
                vb = __hip_atomic_load(myflg + 64 + lane, __ATOMIC_RELAXED,
                                       __HIP_MEMORY_SCOPE_AGENT);
            }
            asm volatile("" ::: "memory");
        }

        // ---------- h-part: 64 agent-scope 8B loads issued as ONE batch
        //            into named registers, then 16 MFMA groups ----------
        {
            const size_t zrow = ((size_t)(p * 2 + dir) * BB + b) * HH + quad * 8;
            const unsigned long long* zhq = (const unsigned long long*)(hspl + zrow);
            const unsigned long long* zlq =
                (const unsigned long long*)(hspl + HSPL_PLANE + zrow);

#define HDECL(i)                                                              \
            const unsigned long long ha##i =                                  \
                __hip_atomic_load(zhq + (i) * 8 + 0, __ATOMIC_RELAXED,        \
                                  __HIP_MEMORY_SCOPE_AGENT);                  \
            const unsigned long long hb##i =                                  \
                __hip_atomic_load(zhq + (i) * 8 + 1, __ATOMIC_RELAXED,        \
                                  __HIP_MEMORY_SCOPE_AGENT);                  \
            const unsigned long long hc##i =                                  \
                __hip_atomic_load(zlq + (i) * 8 + 0, __ATOMIC_RELAXED,        \
                                  __HIP_MEMORY_SCOPE_AGENT);                  \
            const unsigned long long hd##i =                                  \
                __hip_atomic_load(zlq + (i) * 8 + 1, __ATOMIC_RELAXED,        \
                                  __HIP_MEMORY_SCOPE_AGENT);

            HDECL(0)  HDECL(1)  HDECL(2)  HDECL(3)
            HDECL(4)  HDECL(5)  HDECL(6)  HDECL(7)
            HDECL(8)  HDECL(9)  HDECL(10) HDECL(11)
            HDECL(12) HDECL(13) HDECL(14) HDECL(15)
#undef HDECL

#define HMFMA(i)                                                              \
            {                                                                 \
                union { unsigned long long q[2]; short8 v; } uh, ul;          \
                uh.q[0] = ha##i; uh.q[1] = hb##i;                             \
                ul.q[0] = hc##i; ul.q[1] = hd##i;                             \
                const short8 whi = wlds[(0 * 32 + 16 + (i)) * 64 + lane];     \
                const short8 wlo = wlds[(1 * 32 + 16 + (i)) * 64 + lane];     \
                acc = __builtin_amdgcn_mfma_f32_16x16x32_bf16(whi, uh.v, acc, 0, 0, 0); \
                acc = __builtin_amdgcn_mfma_f32_16x16x32_bf16(whi, ul.v, acc, 0, 0, 0); \
                acc = __builtin_amdgcn_mfma_f32_16x16x32_bf16(wlo, uh.v, acc, 0, 0, 0); \
            }

            HMFMA(0)  HMFMA(1)  HMFMA(2)  HMFMA(3)
            HMFMA(4)  HMFMA(5)  HMFMA(6)  HMFMA(7)
            HMFMA(8)  HMFMA(9)  HMFMA(10) HMFMA(11)
            HMFMA(12) HMFMA(13) HMFMA(14) HMFMA(15)
#undef HMFMA
        }

        // ---------- bias + per-wave exchange ----------
        #pragma unroll
        for (int r2 = 0; r2 < 4; ++r2)
            exw[(quad * 4 + r2) * 16 + nn] = acc[r2] + bias_arr[r2];
        float pg[4];
        #pragma unroll
        for (int g_ = 0; g_ < 4; ++g_)
            pg[g_] = exw[(g_ * 4 + quad) * 16 + nn];

        const float f_  = sigm_(pg[0]);
        const float i_  = sigm_(pg[1]);
        const float ct  = tanh_(pg[2]);
        const float o_  = sigm_(pg[3]);
        const float c_  = (f_ + i_) * ct;      // faithful: prev cell unused
        const float hn  = o_ * tanh_(c_);

        const unsigned hib = f2bf_bits(hn);
        const float hif = __builtin_bit_cast(float, hib << 16);
        const unsigned lob = f2bf_bits(hn - hif);
        stg[(0 * 4 + quad) * 64 + b] = (unsigned short)hib;
        stg[(1 * 4 + quad) * 64 + b] = (unsigned short)lob;
        hist[(((size_t)dir * SS + s) * HH + h) * BB + b] = hn;
        __syncthreads();

        // ---------- publish: packed dword write-through stores ----------
        {
            const int plane = tid >> 7;          // 0 hi, 1 lo
            const int d     = tid & 127;
            const int pb    = d >> 1;
            const int pair  = d & 1;
            const unsigned v0 = stg[(plane * 4 + pair * 2 + 0) * 64 + pb];
            const unsigned v1 = stg[(plane * 4 + pair * 2 + 1) * 64 + pb];
            const unsigned val = v0 | (v1 << 16);
            const size_t soff = ((size_t)((p ^ 1) * 2 + dir) * BB + pb) * HH
                                + h0 + pair * 2;
            unsigned* dst = (unsigned*)(hspl + (size_t)plane * HSPL_PLANE + soff);
            __hip_atomic_store(dst, val, __ATOMIC_RELAXED,
                               __HIP_MEMORY_SCOPE_AGENT);
        }
        asm volatile("s_waitcnt vmcnt(0)" ::: "memory");
        __syncthreads();
        if (tid == 0)
            __hip_atomic_store(myflg + wlocal, (unsigned)(t + 1),
                               __ATOMIC_RELAXED, __HIP_MEMORY_SCOPE_AGENT);
    }
}

// ---------------------------------------------------------------------------
__global__ __launch_bounds__(256)
void pool_k(const float* __restrict__ hist, float* __restrict__ pooled)
{
    const int i = blockIdx.x * 256 + threadIdx.x;   // i = h*64 + b
    float m = -2.0f;
    for (int s = 0; s < SS; ++s) {
        const float a = hist[(size_t)s * (HH * BB) + i];
        const float c = hist[(size_t)(SS + s) * (HH * BB) + i];
        m = fmaxf(m, tanhf(a * c));
    }
    pooled[i] = m;
}

__global__ __launch_bounds__(256)
void outgemm_k(const float* __restrict__ pooled, const float* __restrict__ Wout,
               const float* __restrict__ bout, float* __restrict__ out)
{
    const int c   = blockIdx.x;
    const int tid = threadIdx.x;
    const int b   = tid & 63;
    const int q   = __builtin_amdgcn_readfirstlane(tid >> 6);
    float p = 0.0f;
    for (int j = 0; j < 128; ++j) {
        const int h = q * 128 + j;
        p = fmaf(pooled[(size_t)h * BB + b], Wout[c * HH + h], p);
    }
    __shared__ float red[4][BB];
    red[q][b] = p;
    __syncthreads();
    if (tid < BB)
        out[tid * CC + c] = red[0][tid] + red[1][tid] + red[2][tid] + red[3][tid] + bout[c];
}

// ---------------------------------------------------------------------------
extern "C" void kernel_launch(void* const* d_in, const int* in_sizes, int n_in,
                              void* d_out, int out_size, void* d_ws, size_t ws_size,
                              hipStream_t stream)
{
    const int*   x     = (const int*)d_in[0];
    const float* embed = (const float*)d_in[1];
    const float* fwd_W = (const float*)d_in[2];
    const float* fwd_b = (const float*)d_in[3];
    const float* bwd_W = (const float*)d_in[4];
    const float* bwd_b = (const float*)d_in[5];
    const float* Wout  = (const float*)d_in[6];
    const float* bout  = (const float*)d_in[7];
    float* out = (float*)d_out;

    char* wsb = (char*)d_ws;
    short*    xef    = (short*)(wsb + OFF_XEF);
    short*    hspl   = (short*)(wsb + OFF_HSPL);
    unsigned* flg    = (unsigned*)(wsb + OFF_FLG);
    float*    hist   = (float*)(wsb + OFF_HIST);
    float*    pooled = (float*)(wsb + OFF_POOLED);   // overlays hspl (dead)

    gather_split_k<<<SS, 256, 0, stream>>>(x, embed, xef);
    zero_k<<<512, 256, 0, stream>>>((unsigned*)(wsb + OFF_HSPL),
                                    (int)((524288 + 1024) / 4));

    hipFuncSetAttribute((const void*)bilstm_recur_k,
                        hipFuncAttributeMaxDynamicSharedMemorySize, 70656);
    void* args[] = {(void*)&xef, (void*)&fwd_W, (void*)&bwd_W,
                    (void*)&fwd_b, (void*)&bwd_b,
                    (void*)&hspl, (void*)&hist, (void*)&flg};
    hipLaunchCooperativeKernel((void*)bilstm_recur_k, dim3(256), dim3(256),
                               args, 70656, stream);

    pool_k<<<128, 256, 0, stream>>>(hist, pooled);
    outgemm_k<<<CC, 256, 0, stream>>>(pooled, Wout, bout, out);
}